// Round 2
// baseline (219.694 us; speedup 1.0000x reference)
//
#include <hip/hip_runtime.h>
#include <stdint.h>
#include <stddef.h>

// Reference collapse:
//   softmax over k sums to 1 and the einsum applies it pointwise to v,
//   so out = conv1x1(conv1x1(x, W_v, b_v), W_proj, b_proj)
//          = (W_proj @ W_v) @ x  + (W_proj @ b_v + b_proj)
// One 192x192 bf16-MFMA GEMM over 8*16384 pixels. Memory-bound (~150-200 MB HBM).
//
// R2: LDS laid out in MFMA-fragment order (16B lane-slots) -> zero bank
// conflicts on both ds_write_b128 and ds_read_b128; B frags read once per
// (pt,ks); A cached in registers; 512-thread blocks, wave = 48ch x 32px.

#define CDIM 192
#define HWPX 16384

typedef __attribute__((ext_vector_type(8))) short short8;
typedef __attribute__((ext_vector_type(4))) float floatx4;

__device__ __forceinline__ unsigned short f2bf(float f) {
    union { float f; unsigned int u; } v; v.f = f;
    return (unsigned short)((v.u + 0x7FFFu + ((v.u >> 16) & 1u)) >> 16);  // RTNE
}

// ---- prep: M = W_proj @ W_v (bf16), bias = W_proj @ b_v + b_proj ----
__global__ __launch_bounds__(192) void prep_kernel(
    const float* __restrict__ w_qkv, const float* __restrict__ b_qkv,
    const float* __restrict__ w_proj, const float* __restrict__ b_proj,
    unsigned short* __restrict__ Mb, float* __restrict__ bias)
{
    const int o = blockIdx.x, c = threadIdx.x;
    const float* wpr = w_proj + o * CDIM;
    const float* wv  = w_qkv + 2 * CDIM * CDIM;  // v-rows of w_qkv
    float a0 = 0.f, a1 = 0.f, a2 = 0.f, a3 = 0.f;  // 4 chains: break dep latency
    #pragma unroll 12
    for (int k = 0; k < CDIM; k += 4) {
        a0 = fmaf(wpr[k + 0], wv[(k + 0) * CDIM + c], a0);
        a1 = fmaf(wpr[k + 1], wv[(k + 1) * CDIM + c], a1);
        a2 = fmaf(wpr[k + 2], wv[(k + 2) * CDIM + c], a2);
        a3 = fmaf(wpr[k + 3], wv[(k + 3) * CDIM + c], a3);
    }
    Mb[o * CDIM + c] = f2bf((a0 + a1) + (a2 + a3));

    __shared__ float red[CDIM];
    red[c] = wpr[c] * b_qkv[2 * CDIM + c];
    __syncthreads();
    if (c < 64) {
        float v = red[c] + red[c + 64] + red[c + 128];
        #pragma unroll
        for (int off = 32; off > 0; off >>= 1) v += __shfl_down(v, off);
        if (c == 0) bias[o] = v + b_proj[o];
    }
}

// ---- main: out[b, :, p0:p0+64] = M @ x[b, :, p0:p0+64] + bias ----
// LDS fragment order: frag f = pt*6+ks (pt: 16-px group 0..3, ks: 32-ch group 0..5)
// slot (f, lane=(q,n)) holds Xbf16[c = ks*32 + q*8 + j][p = pt*16 + n], j=0..7.
// Reads AND writes are addr = base + lane*16 -> conflict-free.
__global__ __launch_bounds__(512, 4) void fused_kernel(
    const float* __restrict__ x,
    const unsigned short* __restrict__ Mb,
    const float* __restrict__ bias,
    float* __restrict__ out)
{
    __shared__ short8 Xl[24 * 64];  // 24 KiB

    const int tid  = threadIdx.x;
    const int bid  = blockIdx.x;
    const int b    = bid >> 8;          // 256 pixel-tiles per batch
    const int p0   = (bid & 255) << 6;  // 64 pixels per tile

    const int lane = tid & 63;
    const int wv8  = tid >> 6;    // wave 0..7
    const int n    = lane & 15;   // MFMA col / A-row lane
    const int q    = lane >> 4;   // MFMA quad

    // ---- stage x tile (192c x 64p fp32) -> LDS bf16, fragment order ----
    const float* xb = x + (size_t)b * CDIM * HWPX + p0;
    #pragma unroll
    for (int i = 0; i < 3; ++i) {
        const int f  = i * 8 + wv8;       // frag 0..23, wave-uniform
        const int pt = f / 6, ks = f % 6;
        const float* src = xb + (size_t)(ks * 32 + q * 8) * HWPX + (pt * 16 + n);
        float v[8];
        #pragma unroll
        for (int j = 0; j < 8; ++j) v[j] = src[(size_t)j * HWPX];
        short8 fr;
        #pragma unroll
        for (int j = 0; j < 8; ++j) fr[j] = (short)f2bf(v[j]);
        Xl[f * 64 + lane] = fr;           // ds_write_b128, lane-sequential
    }
    __syncthreads();

    // ---- compute: wave = output channels [w2*48, w2*48+48) x pixels [wp*32, +32) ----
    const int w2 = wv8 & 3;   // channel quarter
    const int wp = wv8 >> 2;  // pixel half

    short8 a[3][6];  // A[m=n][k=ks*32+q*8+j] for 3 o-tiles
    #pragma unroll
    for (int t = 0; t < 3; ++t) {
        const unsigned short* ab = Mb + (size_t)((w2 * 3 + t) * 16 + n) * CDIM + q * 8;
        #pragma unroll
        for (int ks = 0; ks < 6; ++ks)
            a[t][ks] = *(const short8*)(ab + ks * 32);
    }

    floatx4 acc[3][2];
    #pragma unroll
    for (int t = 0; t < 3; ++t)
        #pragma unroll
        for (int ph = 0; ph < 2; ++ph)
            acc[t][ph] = (floatx4){0.f, 0.f, 0.f, 0.f};

    #pragma unroll
    for (int ph = 0; ph < 2; ++ph) {
        const int pt = wp * 2 + ph;
        #pragma unroll
        for (int ks = 0; ks < 6; ++ks) {
            short8 bf = Xl[(pt * 6 + ks) * 64 + lane];  // ds_read_b128, lane-sequential
            #pragma unroll
            for (int t = 0; t < 3; ++t)
                acc[t][ph] = __builtin_amdgcn_mfma_f32_16x16x32_bf16(
                    a[t][ks], bf, acc[t][ph], 0, 0, 0);
        }
    }

    // ---- store: D row = q*4 + r (channel), col = n (pixel) ----
    float* ob = out + (size_t)b * CDIM * HWPX + p0;
    #pragma unroll
    for (int t = 0; t < 3; ++t) {
        #pragma unroll
        for (int r = 0; r < 4; ++r) {
            const int o = (w2 * 3 + t) * 16 + q * 4 + r;
            const float bo = bias[o];
            float* orow = ob + (size_t)o * HWPX + n;
            #pragma unroll
            for (int ph = 0; ph < 2; ++ph)
                orow[(wp * 2 + ph) * 16] = acc[t][ph][r] + bo;
        }
    }
}

extern "C" void kernel_launch(void* const* d_in, const int* in_sizes, int n_in,
                              void* d_out, int out_size, void* d_ws, size_t ws_size,
                              hipStream_t stream) {
    const float* x      = (const float*)d_in[0];
    const float* w_qkv  = (const float*)d_in[1];
    const float* b_qkv  = (const float*)d_in[2];
    // d_in[3] = w_attn, d_in[4] = b_attn: mathematically unused (softmax sums to 1)
    const float* w_proj = (const float*)d_in[5];
    const float* b_proj = (const float*)d_in[6];
    float* out = (float*)d_out;

    unsigned short* Mb = (unsigned short*)d_ws;                       // 192*192 bf16
    float* bias = (float*)((char*)d_ws + CDIM * CDIM * sizeof(unsigned short));

    const int B = in_sizes[0] / (CDIM * HWPX);  // 8

    prep_kernel<<<CDIM, CDIM, 0, stream>>>(w_qkv, b_qkv, w_proj, b_proj, Mb, bias);
    fused_kernel<<<B * 256, 512, 0, stream>>>(x, Mb, bias, out);
}

// Round 3
// 209.441 us; speedup vs baseline: 1.0490x; 1.0490x over previous
//
#include <hip/hip_runtime.h>
#include <stdint.h>
#include <stddef.h>

// Reference collapse:
//   softmax over k sums to 1 and the einsum applies it pointwise to v,
//   so out = conv1x1(conv1x1(x, W_v, b_v), W_proj, b_proj)
//          = (W_proj @ W_v) @ x  + (W_proj @ b_v + b_proj)
// One 192x192 bf16-MFMA GEMM over 8*16384 pixels. Memory-bound (~150 MB HBM,
// ~24 us floor).
//
// R3 structure: all three memory streams vectorized to 16 B/lane.
//  - loads: lane = (channel-pair, px-quad): 2x global dwordx4, coalesced.
//  - LDS: pair-interleaved bf16 [c/2][px] stride 68 dwords; write b128
//    (uniform banks), frag read = 4 strided b32 (2-way banks = free).
//  - MFMA swapped to D[px][och]: acc float4 = 4 consecutive pixels ->
//    global_store_dwordx4; M^T frags read from L2 as dwordx4.

#define CDIM 192
#define HWPX 16384
#define SROW 68  // dwords per channel-pair row in LDS (64 px + 4 pad)

typedef __attribute__((ext_vector_type(8))) short short8;
typedef __attribute__((ext_vector_type(4))) float floatx4;

__device__ __forceinline__ unsigned int f2bf_u(float f) {
    union { float f; unsigned int u; } v; v.f = f;
    return (v.u + 0x7FFFu + ((v.u >> 16) & 1u)) >> 16;  // RTNE
}
__device__ __forceinline__ unsigned int pack2(float lo, float hi) {
    return f2bf_u(lo) | (f2bf_u(hi) << 16);
}

// ---- prep: M = W_proj @ W_v (bf16), bias = W_proj @ b_v + b_proj ----
__global__ __launch_bounds__(192) void prep_kernel(
    const float* __restrict__ w_qkv, const float* __restrict__ b_qkv,
    const float* __restrict__ w_proj, const float* __restrict__ b_proj,
    unsigned short* __restrict__ Mb, float* __restrict__ bias)
{
    const int o = blockIdx.x, c = threadIdx.x;
    const float* wpr = w_proj + o * CDIM;
    const float* wv  = w_qkv + 2 * CDIM * CDIM;  // v-rows of w_qkv
    float a0 = 0.f, a1 = 0.f, a2 = 0.f, a3 = 0.f;
    #pragma unroll 12
    for (int k = 0; k < CDIM; k += 4) {
        a0 = fmaf(wpr[k + 0], wv[(k + 0) * CDIM + c], a0);
        a1 = fmaf(wpr[k + 1], wv[(k + 1) * CDIM + c], a1);
        a2 = fmaf(wpr[k + 2], wv[(k + 2) * CDIM + c], a2);
        a3 = fmaf(wpr[k + 3], wv[(k + 3) * CDIM + c], a3);
    }
    Mb[o * CDIM + c] = (unsigned short)f2bf_u((a0 + a1) + (a2 + a3));

    __shared__ float red[CDIM];
    red[c] = wpr[c] * b_qkv[2 * CDIM + c];
    __syncthreads();
    if (c < 64) {
        float v = red[c] + red[c + 64] + red[c + 128];
        #pragma unroll
        for (int off = 32; off > 0; off >>= 1) v += __shfl_down(v, off);
        if (c == 0) bias[o] = v + b_proj[o];
    }
}

// ---- main: out[b, :, p0:p0+64] = M @ x[b, :, p0:p0+64] + bias ----
__global__ __launch_bounds__(256, 3) void fused_kernel(
    const float* __restrict__ x,
    const unsigned short* __restrict__ Mb,
    const float* __restrict__ bias,
    float* __restrict__ out)
{
    __shared__ unsigned int Xw[96 * SROW];  // 25.5 KiB, [c-pair][px] bf16x2

    const int tid  = threadIdx.x;
    const int bid  = blockIdx.x;
    const int b    = bid >> 8;          // 256 pixel-tiles per batch
    const int p0   = (bid & 255) << 6;  // 64 pixels per tile

    const int lane = tid & 63;
    const int w    = tid >> 6;    // wave 0..3
    const int n    = lane & 15;
    const int q    = lane >> 4;

    // ---- stage x tile (192c x 64p fp32) -> LDS bf16 pair-interleaved ----
    const float* xb = x + (size_t)b * CDIM * HWPX + p0;
    #pragma unroll
    for (int it = 0; it < 6; ++it) {
        const int g = it * 256 + tid;       // 1536 slots = 96 pair-rows x 16 quads
        const int r = g >> 4, a = g & 15;
        const float* s0 = xb + (size_t)(2 * r) * HWPX + 4 * a;
        floatx4 fe = *(const floatx4*)s0;            // channel 2r, px 4a..4a+3
        floatx4 fo = *(const floatx4*)(s0 + HWPX);   // channel 2r+1
        uint4 wd;
        wd.x = pack2(fe[0], fo[0]);
        wd.y = pack2(fe[1], fo[1]);
        wd.z = pack2(fe[2], fo[2]);
        wd.w = pack2(fe[3], fo[3]);
        *(uint4*)&Xw[r * SROW + 4 * a] = wd;         // ds_write_b128
    }
    __syncthreads();

    // ---- compute: wave w -> out-channel tiles {3w, 3w+1, 3w+2}, all 4 px-tiles
    floatx4 acc[3][4];
    #pragma unroll
    for (int t = 0; t < 3; ++t)
        #pragma unroll
        for (int pt = 0; pt < 4; ++pt)
            acc[t][pt] = (floatx4){0.f, 0.f, 0.f, 0.f};

    #pragma unroll
    for (int ks = 0; ks < 6; ++ks) {
        // B = M^T frags: lane(n=och, q): M[ot*16+n][ks*32 + q*8 .. +7], from L2
        short8 mf[3];
        #pragma unroll
        for (int t = 0; t < 3; ++t)
            mf[t] = *(const short8*)(Mb + (size_t)((w * 3 + t) * 16 + n) * CDIM
                                     + ks * 32 + q * 8);
        #pragma unroll
        for (int pt = 0; pt < 4; ++pt) {
            // A = X^T frag: lane(n=px, q): channels ks*32+q*8.. , px pt*16+n
            union { unsigned int u[4]; short8 s; } A;
            const int base = (ks * 16 + q * 4) * SROW + pt * 16 + n;
            A.u[0] = Xw[base];
            A.u[1] = Xw[base + SROW];
            A.u[2] = Xw[base + 2 * SROW];
            A.u[3] = Xw[base + 3 * SROW];
            #pragma unroll
            for (int t = 0; t < 3; ++t)
                acc[t][pt] = __builtin_amdgcn_mfma_f32_16x16x32_bf16(
                    A.s, mf[t], acc[t][pt], 0, 0, 0);
        }
    }

    // ---- store: D[m=px][n=och]: lane holds px q*4..q*4+3 of channel ot*16+n
    float* ob = out + (size_t)b * CDIM * HWPX + p0;
    #pragma unroll
    for (int t = 0; t < 3; ++t) {
        const int o = (w * 3 + t) * 16 + n;
        const float bo = bias[o];
        float* orow = ob + (size_t)o * HWPX + q * 4;
        #pragma unroll
        for (int pt = 0; pt < 4; ++pt) {
            floatx4 v = acc[t][pt];
            v[0] += bo; v[1] += bo; v[2] += bo; v[3] += bo;
            *(floatx4*)(orow + pt * 16) = v;         // global_store_dwordx4
        }
    }
}

extern "C" void kernel_launch(void* const* d_in, const int* in_sizes, int n_in,
                              void* d_out, int out_size, void* d_ws, size_t ws_size,
                              hipStream_t stream) {
    const float* x      = (const float*)d_in[0];
    const float* w_qkv  = (const float*)d_in[1];
    const float* b_qkv  = (const float*)d_in[2];
    // d_in[3] = w_attn, d_in[4] = b_attn: mathematically unused (softmax sums to 1)
    const float* w_proj = (const float*)d_in[5];
    const float* b_proj = (const float*)d_in[6];
    float* out = (float*)d_out;

    unsigned short* Mb = (unsigned short*)d_ws;                       // 192*192 bf16
    float* bias = (float*)((char*)d_ws + CDIM * CDIM * sizeof(unsigned short));

    const int B = in_sizes[0] / (CDIM * HWPX);  // 8

    prep_kernel<<<CDIM, CDIM, 0, stream>>>(w_qkv, b_qkv, w_proj, b_proj, Mb, bias);
    fused_kernel<<<B * 256, 256, 0, stream>>>(x, Mb, bias, out);
}